// Round 12
// baseline (353.302 us; speedup 1.0000x reference)
//
#include <hip/hip_runtime.h>

#define CDIM 700     // 2 heads * 350 units, head-concat
#define UHALF 350
#define NPAD 768     // CDIM padded (GEMM N dim)
#define HS 704       // activation row stride (bf16)

// GEMM tile params: 256x256, BK=64, 512 threads = 8 waves (2M x 4N)
#define TBM 256
#define TBN 256
#define TBK 64
#define NBY2 3       // NPAD / TBN

typedef __attribute__((ext_vector_type(8))) short bf16x8;
typedef __attribute__((ext_vector_type(4))) float f32x4;

__device__ inline short f2bf(float v) {
    unsigned u = __float_as_uint(v);
    unsigned r = (u + 0x7fffu + ((u >> 16) & 1u)) >> 16;
    return (short)r;
}
__device__ inline float bf2f(short s) {
    return __uint_as_float(((unsigned)(unsigned short)s) << 16);
}

__device__ inline void load_lds16(const void* g, void* l) {
    __builtin_amdgcn_global_load_lds(
        (const __attribute__((address_space(1))) unsigned*)g,
        (__attribute__((address_space(3))) unsigned*)l,
        16, 0, 0);
}

#define WAITV8() asm volatile("s_waitcnt vmcnt(8)" ::: "memory")
#define WAITV0() asm volatile("s_waitcnt vmcnt(0)" ::: "memory")
#define FENCE()  asm volatile("" ::: "memory")

// ---------------- packing / conversion ----------------
__global__ void pack_bt(const float* __restrict__ K, short* __restrict__ Bt, int Kin, int Kpad) {
    long i = (long)blockIdx.x * blockDim.x + threadIdx.x;
    long total = (long)NPAD * Kpad;
    if (i >= total) return;
    int c = (int)(i / Kpad), f = (int)(i % Kpad);
    float v = 0.f;
    if (c < CDIM && f < Kin) {
        int h = c / UHALF, u = c % UHALF;
        v = K[((long)h * Kin + f) * UHALF + u];
    }
    Bt[i] = f2bf(v);
}

__global__ void cvt_bf16(const float* __restrict__ X, short* __restrict__ Xb, long total) {
    long i = (long)blockIdx.x * blockDim.x + threadIdx.x;
    if (i >= total) return;
    Xb[i] = f2bf(X[i]);
}

// A: (2, 700, 1) -> asrc[704], adst[704] zero-padded
__global__ void pack_avec(const float* __restrict__ A, float* __restrict__ asrc, float* __restrict__ adst) {
    int i = blockIdx.x * blockDim.x + threadIdx.x;
    if (i >= HS) return;
    if (i < CDIM) {
        int h = i / UHALF, u = i % UHALF;
        asrc[i] = A[h * 2 * UHALF + u];
        adst[i] = A[h * 2 * UHALF + UHALF + u];
    } else {
        asrc[i] = 0.f;
        adst[i] = 0.f;
    }
}

__global__ void pack_decw(const float* __restrict__ w, float* __restrict__ wp) {
    int i = blockIdx.x * blockDim.x + threadIdx.x;
    if (i >= HS) return;
    wp[i] = (i < CDIM) ? w[i] : 0.f;
}

// ---------------- CSR build (by src) ----------------
__global__ void count_kernel(const int* __restrict__ edges, int* __restrict__ cnt, int E) {
    int e = blockIdx.x * blockDim.x + threadIdx.x;
    if (e >= E) return;
    atomicAdd(&cnt[edges[2 * e]], 1);
}

__global__ void scan_kernel(const int* __restrict__ cnt, int* __restrict__ offs, int Nn) {
    __shared__ int part[1024];
    int tid = threadIdx.x;
    int chunk = (Nn + 1023) / 1024;
    int b = tid * chunk;
    int e = min(b + chunk, Nn);
    int s = 0;
    for (int i = b; i < e; ++i) s += cnt[i];
    part[tid] = s;
    __syncthreads();
    for (int d = 1; d < 1024; d <<= 1) {
        int v = (tid >= d) ? part[tid - d] : 0;
        __syncthreads();
        part[tid] += v;
        __syncthreads();
    }
    int pre = (tid == 0) ? 0 : part[tid - 1];
    for (int i = b; i < e; ++i) { offs[i] = pre; pre += cnt[i]; }
    if (tid == 0) offs[Nn] = part[1023];
}

__global__ void fill_kernel(const int* __restrict__ edges, const int* __restrict__ offs,
                            int* __restrict__ fill, int* __restrict__ csr_dst,
                            int* __restrict__ csr_srcn, int E) {
    int e = blockIdx.x * blockDim.x + threadIdx.x;
    if (e >= E) return;
    int s = edges[2 * e], d = edges[2 * e + 1];
    int pos = offs[s] + atomicAdd(&fill[s], 1);
    csr_dst[pos] = d;
    csr_srcn[pos] = s;
}

// -------- per-edge attention weights --------
__global__ void ew_kernel(const int* __restrict__ csr_srcn, const int* __restrict__ csr_dst,
                          const float* __restrict__ s_src, const float* __restrict__ s_dst,
                          float2* __restrict__ ew, int Nn, int E) {
    int e = blockIdx.x * blockDim.x + threadIdx.x;
    if (e >= E) return;
    int s = csr_srcn[e], d = csr_dst[e];
    float x0 = s_src[s] + s_dst[d];
    float x1 = s_src[Nn + s] + s_dst[Nn + d];
    x0 = (x0 >= 0.f) ? x0 : 0.2f * x0;
    x1 = (x1 >= 0.f) ? x1 : 0.2f * x1;
    x0 = fminf(fmaxf(x0, -2.f), 2.f);
    x1 = fminf(fmaxf(x1, -2.f), 2.f);
    ew[e] = make_float2(expf(x0), expf(x1));
}

// ------- bf16 MFMA GEMM: 256x256 8-wave, BK=64, counted vmcnt(8), XOR-swizzle, XCD swizzle -------
__global__ __launch_bounds__(512, 2) void gemm_mfma(const short* __restrict__ Xb, const short* __restrict__ Bt,
                                                    short* __restrict__ hb, int M, int Kpad) {
    __shared__ short sA[2][TBM * TBK];   // [row][k], 64 shorts/row, slot-swizzled
    __shared__ short sB[2][TBN * TBK];   // [col][k]
    int tid = threadIdx.x;
    int wave = tid >> 6, lane = tid & 63;

    // bijective XCD swizzle; by inner -> 3 consecutive wgids share A row panel per XCD
    int nwg = gridDim.x;
    int id = blockIdx.x;
    int q = nwg >> 3, r = nwg & 7;
    int xcd = id & 7, rk = id >> 3;
    int wgid = (xcd < r ? xcd * (q + 1) : r * (q + 1) + (xcd - r) * q) + rk;
    int by = wgid % NBY2;
    int bx = wgid / NBY2;
    int brow = bx * TBM;
    int bcol = by * TBN;
    int wm = wave >> 2, wn = wave & 3;    // wave tile: rows wm*128.., cols wn*64..
    f32x4 acc[8][4] = {};

    // staging map: per thread 4 A-loads + 4 B-loads per K-tile.
    // linear idx = j*512 + tid -> row = idx>>3 (0..255), slot = idx&7.
    // swizzle: LDS (row, slot) holds global (row, slot ^ (row&7)).
    const short* aSrc[4];
    const short* bSrc[4];
    int ldsOff[4];
#pragma unroll
    for (int j = 0; j < 4; ++j) {
        int idx = j * 512 + tid;
        int row = idx >> 3, slot = idx & 7;
        int ss = slot ^ (row & 7);
        int ar = brow + row; if (ar >= M) ar = M - 1;
        aSrc[j] = Xb + (long)ar * Kpad + ss * 8;
        bSrc[j] = Bt + (long)(bcol + row) * Kpad + ss * 8;
        ldsOff[j] = idx * 8;
    }

#define STAGE(buf, kt)                                                     \
    do {                                                                   \
        _Pragma("unroll")                                                  \
        for (int j = 0; j < 4; ++j) {                                      \
            load_lds16(aSrc[j] + (kt) * TBK, &sA[buf][ldsOff[j]]);         \
            load_lds16(bSrc[j] + (kt) * TBK, &sB[buf][ldsOff[j]]);         \
        }                                                                  \
    } while (0)

    int nt = Kpad / TBK;
    STAGE(0, 0);

    // fragment read addressing (16x16x32): k = kk*32 + (lane>>4)*8 -> slot = kk*4+hi, ^ (lane&7)
    int r16 = lane & 15, hi = lane >> 4, sw = lane & 7;
    const int so0 = (((0 + hi) ^ sw)) * 8;   // kk=0 slot offset (shorts)
    const int so1 = (((4 + hi) ^ sw)) * 8;   // kk=1
    const int aBase = (wm * 128 + r16) * TBK;
    const int bBase = (wn * 64 + r16) * TBK;

    for (int t = 0; t < nt; ++t) {
        int c = t & 1;
        if (t + 1 < nt) {
            STAGE(c ^ 1, t + 1);
            WAITV8();            // oldest 8 (tile t) landed; tile t+1's 8 stay in flight
        } else {
            WAITV0();
        }
        __builtin_amdgcn_s_barrier();
        __builtin_amdgcn_sched_barrier(0);

        const short* pb = &sB[c][0] + bBase;
        bf16x8 bf0[4], bf1[4];
#pragma unroll
        for (int nb = 0; nb < 4; ++nb) {
            bf0[nb] = *(const bf16x8*)(pb + nb * 16 * TBK + so0);
            bf1[nb] = *(const bf16x8*)(pb + nb * 16 * TBK + so1);
        }
        const short* pa = &sA[c][0] + aBase;
        __builtin_amdgcn_s_setprio(1);
#pragma unroll
        for (int mb = 0; mb < 8; ++mb) {
            bf16x8 a0 = *(const bf16x8*)(pa + mb * 16 * TBK + so0);
            bf16x8 a1 = *(const bf16x8*)(pa + mb * 16 * TBK + so1);
#pragma unroll
            for (int nb = 0; nb < 4; ++nb) {
                acc[mb][nb] = __builtin_amdgcn_mfma_f32_16x16x32_bf16(a0, bf0[nb], acc[mb][nb], 0, 0, 0);
                acc[mb][nb] = __builtin_amdgcn_mfma_f32_16x16x32_bf16(a1, bf1[nb], acc[mb][nb], 0, 0, 0);
            }
        }
        __builtin_amdgcn_s_setprio(0);

        FENCE();
        __builtin_amdgcn_s_barrier();      // all waves done reading buf c before t+2's stage overwrites it
        __builtin_amdgcn_sched_barrier(0);
    }
#undef STAGE

    // epilogue: C/D layout col = lane&15, row = hi*4 + rr
    int crow = brow + wm * 128;
    int ccol = bcol + wn * 64 + r16;
#pragma unroll
    for (int mb = 0; mb < 8; ++mb) {
#pragma unroll
        for (int rr = 0; rr < 4; ++rr) {
            int gr = crow + mb * 16 + hi * 4 + rr;
            if (gr >= M) continue;
#pragma unroll
            for (int nb = 0; nb < 4; ++nb) {
                int gc = ccol + nb * 16;
                if (gc < CDIM) hb[(long)gr * HS + gc] = f2bf(acc[mb][nb][rr]);
            }
        }
    }
}

// ---------------- per-node attention scores ----------------
__global__ __launch_bounds__(256) void score_kernel(const short* __restrict__ hb, const float* __restrict__ asrc,
                                                    const float* __restrict__ adst, float* __restrict__ s_src,
                                                    float* __restrict__ s_dst, int Nn) {
    int wave = threadIdx.x >> 6, lane = threadIdx.x & 63;
    int u = blockIdx.x * 4 + wave;
    if (u >= Nn) return;
    const short4* hrow = (const short4*)(hb + (long)u * HS);
    float ps0 = 0.f, pd0 = 0.f, ps1 = 0.f, pd1 = 0.f;
    for (int it = lane; it < HS / 4; it += 64) {
        short4 v = hrow[it];
        int col = it * 4;
#pragma unroll
        for (int e = 0; e < 4; ++e) {
            float f = bf2f(((const short*)&v)[e]);
            int c = col + e;
            float a = asrc[c], d = adst[c];
            if (c < UHALF) { ps0 += f * a; pd0 += f * d; }
            else           { ps1 += f * a; pd1 += f * d; }
        }
    }
    for (int d = 32; d; d >>= 1) {
        ps0 += __shfl_down(ps0, d); pd0 += __shfl_down(pd0, d);
        ps1 += __shfl_down(ps1, d); pd1 += __shfl_down(pd1, d);
    }
    if (lane == 0) {
        s_src[u] = ps0; s_dst[u] = pd0;
        s_src[Nn + u] = ps1; s_dst[Nn + u] = pd1;
    }
}

// -------- per-node aggregation: one WAVE per node, 4-edge unroll (12 gathers in flight) --------
__global__ __launch_bounds__(256) void aggregate_kernel(const short* __restrict__ hb, const float2* __restrict__ ew,
                                                        const int* __restrict__ offs, const int* __restrict__ csr_dst,
                                                        short* __restrict__ Y, int Nn) {
    int u = blockIdx.x * 4 + (threadIdx.x >> 6);
    if (u >= Nn) return;
    int lane = threadIdx.x & 63;
    int beg = offs[u], end = offs[u + 1];

    f32x4 facc[3] = {};
    float den0 = 0.f, den1 = 0.f;

    int it0 = lane, it1 = lane + 64, it2 = lane + 128;  // short4 indices, HS/4=176
    bool has2 = (it2 < HS / 4);
    int mid = it1 * 4;  // cols 256..511: head boundary at 350
    int e = beg;
    for (; e + 3 < end; e += 4) {
        int v0 = csr_dst[e], v1 = csr_dst[e + 1], v2 = csr_dst[e + 2], v3 = csr_dst[e + 3];
        float2 w0 = ew[e], w1 = ew[e + 1], w2 = ew[e + 2], w3 = ew[e + 3];
        const short4* h0 = (const short4*)(hb + (long)v0 * HS);
        const short4* h1 = (const short4*)(hb + (long)v1 * HS);
        const short4* h2 = (const short4*)(hb + (long)v2 * HS);
        const short4* h3 = (const short4*)(hb + (long)v3 * HS);
        short4 a00 = h0[it0], a01 = h0[it1];
        short4 a10 = h1[it0], a11 = h1[it1];
        short4 a20 = h2[it0], a21 = h2[it1];
        short4 a30 = h3[it0], a31 = h3[it1];
        short4 z = make_short4(0, 0, 0, 0);
        short4 a02 = has2 ? h0[it2] : z, a12 = has2 ? h1[it2] : z;
        short4 a22 = has2 ? h2[it2] : z, a32 = has2 ? h3[it2] : z;
        den0 += w0.x + w1.x + w2.x + w3.x;
        den1 += w0.y + w1.y + w2.y + w3.y;
#pragma unroll
        for (int ee = 0; ee < 4; ++ee) {
            float s0 = (mid + ee < UHALF) ? w0.x : w0.y;
            float s1 = (mid + ee < UHALF) ? w1.x : w1.y;
            float s2 = (mid + ee < UHALF) ? w2.x : w2.y;
            float s3 = (mid + ee < UHALF) ? w3.x : w3.y;
            facc[0][ee] += bf2f(((const short*)&a00)[ee]) * w0.x + bf2f(((const short*)&a10)[ee]) * w1.x
                         + bf2f(((const short*)&a20)[ee]) * w2.x + bf2f(((const short*)&a30)[ee]) * w3.x;
            facc[1][ee] += bf2f(((const short*)&a01)[ee]) * s0 + bf2f(((const short*)&a11)[ee]) * s1
                         + bf2f(((const short*)&a21)[ee]) * s2 + bf2f(((const short*)&a31)[ee]) * s3;
            facc[2][ee] += bf2f(((const short*)&a02)[ee]) * w0.y + bf2f(((const short*)&a12)[ee]) * w1.y
                         + bf2f(((const short*)&a22)[ee]) * w2.y + bf2f(((const short*)&a32)[ee]) * w3.y;
        }
    }
    for (; e < end; ++e) {
        int va = csr_dst[e];
        float2 wA = ew[e];
        const short4* hva = (const short4*)(hb + (long)va * HS);
        short4 a0 = hva[it0], a1 = hva[it1];
        short4 a2 = has2 ? hva[it2] : make_short4(0, 0, 0, 0);
        den0 += wA.x; den1 += wA.y;
#pragma unroll
        for (int ee = 0; ee < 4; ++ee) {
            float w1sel_a = (mid + ee < UHALF) ? wA.x : wA.y;
            facc[0][ee] += bf2f(((const short*)&a0)[ee]) * wA.x;
            facc[1][ee] += bf2f(((const short*)&a1)[ee]) * w1sel_a;
            facc[2][ee] += bf2f(((const short*)&a2)[ee]) * wA.y;
        }
    }

    // every lane holds full denominators (broadcast scalar loads)
    float inv0 = (den0 > 0.f) ? 1.f / den0 : 0.f;
    float inv1 = (den1 > 0.f) ? 1.f / den1 : 0.f;
    short* yrow = Y + (long)u * HS;
    short4 o0, o1, o2;
#pragma unroll
    for (int ee = 0; ee < 4; ++ee) {
        ((short*)&o0)[ee] = f2bf(fmaxf(facc[0][ee] * inv0, 0.f));                         // cols < 256: head0
        ((short*)&o1)[ee] = f2bf(fmaxf(facc[1][ee] * ((mid + ee < UHALF) ? inv0 : inv1), 0.f));
        int c2 = it2 * 4 + ee;
        ((short*)&o2)[ee] = (c2 < CDIM) ? f2bf(fmaxf(facc[2][ee] * inv1, 0.f)) : (short)0;
    }
    ((short4*)yrow)[it0] = o0;
    ((short4*)yrow)[it1] = o1;
    if (has2) ((short4*)yrow)[it2] = o2;
}

// ---------------- decoder: 2 pairs per wave (4 row streams in flight) ----------------
__global__ __launch_bounds__(256) void decode_kernel(const short* __restrict__ O, const int* __restrict__ r_idx,
                                                     const int* __restrict__ c_idx, const float* __restrict__ wp,
                                                     const float* __restrict__ dec_b, float* __restrict__ out, int M) {
    int wave = threadIdx.x >> 6, lane = threadIdx.x & 63;
    long m0 = (long)blockIdx.x * 8 + wave;
    long m1 = m0 + 4;
    if (m0 >= M) return;
    bool has1 = (m1 < M);
    int r0 = r_idx[m0], c0 = c_idx[m0];
    int r1 = has1 ? r_idx[m1] : r0;
    int c1 = has1 ? c_idx[m1] : c0;
    const short4* or0 = (const short4*)(O + (long)r0 * HS);
    const short4* oc0 = (const short4*)(O + (long)c0 * HS);
    const short4* or1 = (const short4*)(O + (long)r1 * HS);
    const short4* oc1 = (const short4*)(O + (long)c1 * HS);
    const float4* wv = (const float4*)wp;
    float s0 = 0.f, s1 = 0.f;
    for (int it = lane; it < HS / 4; it += 64) {
        short4 a0 = or0[it], b0 = oc0[it];
        short4 a1 = or1[it], b1 = oc1[it];
        float4 w = wv[it];
        s0 += fabsf(bf2f(a0.x) - bf2f(b0.x)) * w.x + fabsf(bf2f(a0.y) - bf2f(b0.y)) * w.y
            + fabsf(bf2f(a0.z) - bf2f(b0.z)) * w.z + fabsf(bf2f(a0.w) - bf2f(b0.w)) * w.w;
        s1 += fabsf(bf2f(a1.x) - bf2f(b1.x)) * w.x + fabsf(bf2f(a1.y) - bf2f(b1.y)) * w.y
            + fabsf(bf2f(a1.z) - bf2f(b1.z)) * w.z + fabsf(bf2f(a1.w) - bf2f(b1.w)) * w.w;
    }
    for (int d = 32; d; d >>= 1) {
        s0 += __shfl_down(s0, d);
        s1 += __shfl_down(s1, d);
    }
    if (lane == 0) {
        out[m0] = s0 + dec_b[0];
        if (has1) out[m1] = s1 + dec_b[0];
    }
}

extern "C" void kernel_launch(void* const* d_in, const int* in_sizes, int n_in,
                              void* d_out, int out_size, void* d_ws, size_t ws_size,
                              hipStream_t stream) {
    (void)n_in; (void)out_size; (void)ws_size;
    const float* node_feats = (const float*)d_in[0];
    const int* edges = (const int*)d_in[1];
    const int* r_idx = (const int*)d_in[2];
    const int* c_idx = (const int*)d_in[3];
    const float* kmats[3] = {(const float*)d_in[4], (const float*)d_in[6], (const float*)d_in[8]};
    const float* amats[3] = {(const float*)d_in[5], (const float*)d_in[7], (const float*)d_in[9]};
    const float* dec_w = (const float*)d_in[10];
    const float* dec_b = (const float*)d_in[11];
    float* out = (float*)d_out;

    const int F0 = 256;
    const int N = in_sizes[0] / F0;
    const int E = in_sizes[1] / 2;
    const int M = in_sizes[2];
    const int KP1 = 256;
    const int KP2 = HS;   // 704

    char* ws = (char*)d_ws;
    size_t off = 0;
    auto alloc = [&](size_t bytes) -> void* {
        void* p = ws + off;
        off += (bytes + 255) & ~(size_t)255;
        return p;
    };
    // Workspace ~60.5 MB (under the R5-proven budget).
    // layer-0 bf16 input (N x 256) lives in the low bytes of Xb (stride 256);
    // layer-0's GEMM reads it before layer-0's aggregate overwrites Xb (stride 704).
    short* hb   = (short*)alloc((size_t)N * HS * 2);
    short* Xb   = (short*)alloc((size_t)N * HS * 2);
    short* Bt   = (short*)alloc((size_t)NPAD * KP2 * 2);
    float* asrc = (float*)alloc(HS * 4);
    float* adst = (float*)alloc(HS * 4);
    float* decw = (float*)alloc(HS * 4);
    float* s_src = (float*)alloc((size_t)2 * N * 4);
    float* s_dst = (float*)alloc((size_t)2 * N * 4);
    float2* ew   = (float2*)alloc((size_t)E * 8);
    int* offs = (int*)alloc((size_t)(N + 1) * 4);
    int* cnt = (int*)alloc((size_t)N * 4);
    int* fill = (int*)alloc((size_t)N * 4);
    int* csr_dst = (int*)alloc((size_t)E * 4);
    int* csr_srcn = (int*)alloc((size_t)E * 4);

    hipMemsetAsync(cnt, 0, (size_t)N * 4, stream);
    hipMemsetAsync(fill, 0, (size_t)N * 4, stream);

    count_kernel<<<(E + 255) / 256, 256, 0, stream>>>(edges, cnt, E);
    scan_kernel<<<1, 1024, 0, stream>>>(cnt, offs, N);
    fill_kernel<<<(E + 255) / 256, 256, 0, stream>>>(edges, offs, fill, csr_dst, csr_srcn, E);

    long x0t = (long)N * KP1;
    cvt_bf16<<<(int)((x0t + 255) / 256), 256, 0, stream>>>(node_feats, Xb, x0t);
    pack_decw<<<(HS + 255) / 256, 256, 0, stream>>>(dec_w, decw);

    for (int l = 0; l < 3; ++l) {
        int Kpad = (l == 0) ? KP1 : KP2;
        long bt = (long)NPAD * Kpad;
        pack_bt<<<(int)((bt + 255) / 256), 256, 0, stream>>>(kmats[l], Bt, (l == 0) ? F0 : CDIM, Kpad);
        pack_avec<<<(HS + 255) / 256, 256, 0, stream>>>(amats[l], asrc, adst);
        int nbx = (N + TBM - 1) / TBM;
        gemm_mfma<<<nbx * NBY2, 512, 0, stream>>>(Xb, Bt, hb, N, Kpad);
        score_kernel<<<(N + 3) / 4, 256, 0, stream>>>(hb, asrc, adst, s_src, s_dst, N);
        ew_kernel<<<(E + 255) / 256, 256, 0, stream>>>(csr_srcn, csr_dst, s_src, s_dst, ew, N, E);
        aggregate_kernel<<<(N + 3) / 4, 256, 0, stream>>>(hb, ew, offs, csr_dst, Xb, N);
    }
    decode_kernel<<<(int)((M + 7) / 8), 256, 0, stream>>>(Xb, r_idx, c_idx, decw, dec_b, out, M);
}

// Round 13
// 347.884 us; speedup vs baseline: 1.0156x; 1.0156x over previous
//
#include <hip/hip_runtime.h>

#define CDIM 700     // 2 heads * 350 units, head-concat
#define UHALF 350
#define NPAD 768     // CDIM padded (GEMM N dim)
#define HS 704       // activation row stride (bf16)

// GEMM tile params: 256x256, BK=64, 512 threads = 8 waves (2M x 4N)
#define TBM 256
#define TBN 256
#define TBK 64
#define NBY2 3       // NPAD / TBN

typedef __attribute__((ext_vector_type(8))) short bf16x8;
typedef __attribute__((ext_vector_type(4))) float f32x4;

__device__ inline short f2bf(float v) {
    unsigned u = __float_as_uint(v);
    unsigned r = (u + 0x7fffu + ((u >> 16) & 1u)) >> 16;
    return (short)r;
}
__device__ inline float bf2f(short s) {
    return __uint_as_float(((unsigned)(unsigned short)s) << 16);
}

__device__ inline void load_lds16(const void* g, void* l) {
    __builtin_amdgcn_global_load_lds(
        (const __attribute__((address_space(1))) unsigned*)g,
        (__attribute__((address_space(3))) unsigned*)l,
        16, 0, 0);
}

#define WAITV8() asm volatile("s_waitcnt vmcnt(8)" ::: "memory")
#define WAITV0() asm volatile("s_waitcnt vmcnt(0)" ::: "memory")
#define FENCE()  asm volatile("" ::: "memory")

// ---------------- packing: Bt + avec (+decw once), one launch per layer ----------------
__global__ void pack_layer(const float* __restrict__ K, short* __restrict__ Bt, int Kin, int Kpad,
                           const float* __restrict__ A, float* __restrict__ asrc, float* __restrict__ adst,
                           const float* __restrict__ w, float* __restrict__ wp, int do_dec) {
    long i = (long)blockIdx.x * blockDim.x + threadIdx.x;
    long total = (long)NPAD * Kpad;
    if (i < total) {
        int c = (int)(i / Kpad), f = (int)(i % Kpad);
        float v = 0.f;
        if (c < CDIM && f < Kin) {
            int h = c / UHALF, u = c % UHALF;
            v = K[((long)h * Kin + f) * UHALF + u];
        }
        Bt[i] = f2bf(v);
    }
    if (i < HS) {
        if (i < CDIM) {
            int h = (int)i / UHALF, u = (int)i % UHALF;
            asrc[i] = A[h * 2 * UHALF + u];
            adst[i] = A[h * 2 * UHALF + UHALF + u];
        } else {
            asrc[i] = 0.f;
            adst[i] = 0.f;
        }
        if (do_dec) wp[i] = (i < CDIM) ? w[i] : 0.f;
    }
}

__global__ void cvt_bf16(const float* __restrict__ X, short* __restrict__ Xb, long total) {
    long i = (long)blockIdx.x * blockDim.x + threadIdx.x;
    if (i >= total) return;
    Xb[i] = f2bf(X[i]);
}

// ---------------- CSR build (by src) ----------------
__global__ void count_kernel(const int* __restrict__ edges, int* __restrict__ cnt, int E) {
    int e = blockIdx.x * blockDim.x + threadIdx.x;
    if (e >= E) return;
    atomicAdd(&cnt[edges[2 * e]], 1);
}

__global__ void scan_kernel(const int* __restrict__ cnt, int* __restrict__ offs, int Nn) {
    __shared__ int part[1024];
    int tid = threadIdx.x;
    int chunk = (Nn + 1023) / 1024;
    int b = tid * chunk;
    int e = min(b + chunk, Nn);
    int s = 0;
    for (int i = b; i < e; ++i) s += cnt[i];
    part[tid] = s;
    __syncthreads();
    for (int d = 1; d < 1024; d <<= 1) {
        int v = (tid >= d) ? part[tid - d] : 0;
        __syncthreads();
        part[tid] += v;
        __syncthreads();
    }
    int pre = (tid == 0) ? 0 : part[tid - 1];
    for (int i = b; i < e; ++i) { offs[i] = pre; pre += cnt[i]; }
    if (tid == 0) offs[Nn] = part[1023];
}

__global__ void fill_kernel(const int* __restrict__ edges, const int* __restrict__ offs,
                            int* __restrict__ fill, int* __restrict__ csr_dst,
                            int* __restrict__ csr_srcn, int E) {
    int e = blockIdx.x * blockDim.x + threadIdx.x;
    if (e >= E) return;
    int s = edges[2 * e], d = edges[2 * e + 1];
    int pos = offs[s] + atomicAdd(&fill[s], 1);
    csr_dst[pos] = d;
    csr_srcn[pos] = s;
}

// -------- per-edge attention weights --------
__global__ void ew_kernel(const int* __restrict__ csr_srcn, const int* __restrict__ csr_dst,
                          const float* __restrict__ s_src, const float* __restrict__ s_dst,
                          float2* __restrict__ ew, int Nn, int E) {
    int e = blockIdx.x * blockDim.x + threadIdx.x;
    if (e >= E) return;
    int s = csr_srcn[e], d = csr_dst[e];
    float x0 = s_src[s] + s_dst[d];
    float x1 = s_src[Nn + s] + s_dst[Nn + d];
    x0 = (x0 >= 0.f) ? x0 : 0.2f * x0;
    x1 = (x1 >= 0.f) ? x1 : 0.2f * x1;
    x0 = fminf(fmaxf(x0, -2.f), 2.f);
    x1 = fminf(fmaxf(x1, -2.f), 2.f);
    ew[e] = make_float2(expf(x0), expf(x1));
}

// ------- bf16 MFMA GEMM: 256x256 8-wave, BK=64, counted vmcnt(8), XOR-swizzle, XCD swizzle -------
__global__ __launch_bounds__(512, 2) void gemm_mfma(const short* __restrict__ Xb, const short* __restrict__ Bt,
                                                    short* __restrict__ hb, int M, int Kpad) {
    __shared__ short sA[2][TBM * TBK];   // [row][k], 64 shorts/row, slot-swizzled
    __shared__ short sB[2][TBN * TBK];   // [col][k]
    int tid = threadIdx.x;
    int wave = tid >> 6, lane = tid & 63;

    // bijective XCD swizzle; by inner -> 3 consecutive wgids share A row panel per XCD
    int nwg = gridDim.x;
    int id = blockIdx.x;
    int q = nwg >> 3, r = nwg & 7;
    int xcd = id & 7, rk = id >> 3;
    int wgid = (xcd < r ? xcd * (q + 1) : r * (q + 1) + (xcd - r) * q) + rk;
    int by = wgid % NBY2;
    int bx = wgid / NBY2;
    int brow = bx * TBM;
    int bcol = by * TBN;
    int wm = wave >> 2, wn = wave & 3;    // wave tile: rows wm*128.., cols wn*64..
    f32x4 acc[8][4] = {};

    // staging map: per thread 4 A-loads + 4 B-loads per K-tile.
    // linear idx = j*512 + tid -> row = idx>>3 (0..255), slot = idx&7.
    // swizzle: LDS (row, slot) holds global (row, slot ^ (row&7)).
    const short* aSrc[4];
    const short* bSrc[4];
    int ldsOff[4];
#pragma unroll
    for (int j = 0; j < 4; ++j) {
        int idx = j * 512 + tid;
        int row = idx >> 3, slot = idx & 7;
        int ss = slot ^ (row & 7);
        int ar = brow + row; if (ar >= M) ar = M - 1;
        aSrc[j] = Xb + (long)ar * Kpad + ss * 8;
        bSrc[j] = Bt + (long)(bcol + row) * Kpad + ss * 8;
        ldsOff[j] = idx * 8;
    }

#define STAGE(buf, kt)                                                     \
    do {                                                                   \
        _Pragma("unroll")                                                  \
        for (int j = 0; j < 4; ++j) {                                      \
            load_lds16(aSrc[j] + (kt) * TBK, &sA[buf][ldsOff[j]]);         \
            load_lds16(bSrc[j] + (kt) * TBK, &sB[buf][ldsOff[j]]);         \
        }                                                                  \
    } while (0)

    int nt = Kpad / TBK;
    STAGE(0, 0);

    // fragment read addressing (16x16x32): k = kk*32 + (lane>>4)*8 -> slot = kk*4+hi, ^ (lane&7)
    int r16 = lane & 15, hi = lane >> 4, sw = lane & 7;
    const int so0 = (((0 + hi) ^ sw)) * 8;   // kk=0 slot offset (shorts)
    const int so1 = (((4 + hi) ^ sw)) * 8;   // kk=1
    const int aBase = (wm * 128 + r16) * TBK;
    const int bBase = (wn * 64 + r16) * TBK;

    for (int t = 0; t < nt; ++t) {
        int c = t & 1;
        if (t + 1 < nt) {
            STAGE(c ^ 1, t + 1);
            WAITV8();            // oldest 8 (tile t) landed; tile t+1's 8 stay in flight
        } else {
            WAITV0();
        }
        __builtin_amdgcn_s_barrier();
        __builtin_amdgcn_sched_barrier(0);

        const short* pb = &sB[c][0] + bBase;
        bf16x8 bf0[4], bf1[4];
#pragma unroll
        for (int nb = 0; nb < 4; ++nb) {
            bf0[nb] = *(const bf16x8*)(pb + nb * 16 * TBK + so0);
            bf1[nb] = *(const bf16x8*)(pb + nb * 16 * TBK + so1);
        }
        const short* pa = &sA[c][0] + aBase;
        __builtin_amdgcn_s_setprio(1);
#pragma unroll
        for (int mb = 0; mb < 8; ++mb) {
            bf16x8 a0 = *(const bf16x8*)(pa + mb * 16 * TBK + so0);
            bf16x8 a1 = *(const bf16x8*)(pa + mb * 16 * TBK + so1);
#pragma unroll
            for (int nb = 0; nb < 4; ++nb) {
                acc[mb][nb] = __builtin_amdgcn_mfma_f32_16x16x32_bf16(a0, bf0[nb], acc[mb][nb], 0, 0, 0);
                acc[mb][nb] = __builtin_amdgcn_mfma_f32_16x16x32_bf16(a1, bf1[nb], acc[mb][nb], 0, 0, 0);
            }
        }
        __builtin_amdgcn_s_setprio(0);

        FENCE();
        __builtin_amdgcn_s_barrier();      // all waves done reading buf c before t+2's stage overwrites it
        __builtin_amdgcn_sched_barrier(0);
    }
#undef STAGE

    // epilogue: C/D layout col = lane&15, row = hi*4 + rr
    int crow = brow + wm * 128;
    int ccol = bcol + wn * 64 + r16;
#pragma unroll
    for (int mb = 0; mb < 8; ++mb) {
#pragma unroll
        for (int rr = 0; rr < 4; ++rr) {
            int gr = crow + mb * 16 + hi * 4 + rr;
            if (gr >= M) continue;
#pragma unroll
            for (int nb = 0; nb < 4; ++nb) {
                int gc = ccol + nb * 16;
                if (gc < CDIM) hb[(long)gr * HS + gc] = f2bf(acc[mb][nb][rr]);
            }
        }
    }
}

// ---------------- per-node attention scores ----------------
__global__ __launch_bounds__(256) void score_kernel(const short* __restrict__ hb, const float* __restrict__ asrc,
                                                    const float* __restrict__ adst, float* __restrict__ s_src,
                                                    float* __restrict__ s_dst, int Nn) {
    int wave = threadIdx.x >> 6, lane = threadIdx.x & 63;
    int u = blockIdx.x * 4 + wave;
    if (u >= Nn) return;
    const short4* hrow = (const short4*)(hb + (long)u * HS);
    float ps0 = 0.f, pd0 = 0.f, ps1 = 0.f, pd1 = 0.f;
    for (int it = lane; it < HS / 4; it += 64) {
        short4 v = hrow[it];
        int col = it * 4;
#pragma unroll
        for (int e = 0; e < 4; ++e) {
            float f = bf2f(((const short*)&v)[e]);
            int c = col + e;
            float a = asrc[c], d = adst[c];
            if (c < UHALF) { ps0 += f * a; pd0 += f * d; }
            else           { ps1 += f * a; pd1 += f * d; }
        }
    }
    for (int d = 32; d; d >>= 1) {
        ps0 += __shfl_down(ps0, d); pd0 += __shfl_down(pd0, d);
        ps1 += __shfl_down(ps1, d); pd1 += __shfl_down(pd1, d);
    }
    if (lane == 0) {
        s_src[u] = ps0; s_dst[u] = pd0;
        s_src[Nn + u] = ps1; s_dst[Nn + u] = pd1;
    }
}

// -------- per-node aggregation: one WAVE per node, 2-edge unroll (R11 best form) --------
__global__ __launch_bounds__(256) void aggregate_kernel(const short* __restrict__ hb, const float2* __restrict__ ew,
                                                        const int* __restrict__ offs, const int* __restrict__ csr_dst,
                                                        short* __restrict__ Y, int Nn) {
    int u = blockIdx.x * 4 + (threadIdx.x >> 6);
    if (u >= Nn) return;
    int lane = threadIdx.x & 63;
    int beg = offs[u], end = offs[u + 1];

    f32x4 facc[3] = {};
    float den0 = 0.f, den1 = 0.f;

    int it0 = lane, it1 = lane + 64, it2 = lane + 128;  // short4 indices, HS/4=176
    bool has2 = (it2 < HS / 4);
    int mid = it1 * 4;  // cols 256..511: head boundary at 350
    int e = beg;
    for (; e + 1 < end; e += 2) {
        int va = csr_dst[e], vb = csr_dst[e + 1];
        float2 wA = ew[e], wB = ew[e + 1];
        const short4* hva = (const short4*)(hb + (long)va * HS);
        const short4* hvb = (const short4*)(hb + (long)vb * HS);
        short4 a0 = hva[it0], a1 = hva[it1];
        short4 b0 = hvb[it0], b1 = hvb[it1];
        short4 z = make_short4(0, 0, 0, 0);
        short4 a2 = has2 ? hva[it2] : z;
        short4 b2 = has2 ? hvb[it2] : z;
        den0 += wA.x + wB.x; den1 += wA.y + wB.y;
#pragma unroll
        for (int ee = 0; ee < 4; ++ee) {
            float w1sel_a = (mid + ee < UHALF) ? wA.x : wA.y;
            float w1sel_b = (mid + ee < UHALF) ? wB.x : wB.y;
            facc[0][ee] += bf2f(((const short*)&a0)[ee]) * wA.x + bf2f(((const short*)&b0)[ee]) * wB.x;
            facc[1][ee] += bf2f(((const short*)&a1)[ee]) * w1sel_a + bf2f(((const short*)&b1)[ee]) * w1sel_b;
            facc[2][ee] += bf2f(((const short*)&a2)[ee]) * wA.y + bf2f(((const short*)&b2)[ee]) * wB.y;
        }
    }
    if (e < end) {
        int va = csr_dst[e];
        float2 wA = ew[e];
        const short4* hva = (const short4*)(hb + (long)va * HS);
        short4 a0 = hva[it0], a1 = hva[it1];
        short4 a2 = has2 ? hva[it2] : make_short4(0, 0, 0, 0);
        den0 += wA.x; den1 += wA.y;
#pragma unroll
        for (int ee = 0; ee < 4; ++ee) {
            float w1sel_a = (mid + ee < UHALF) ? wA.x : wA.y;
            facc[0][ee] += bf2f(((const short*)&a0)[ee]) * wA.x;
            facc[1][ee] += bf2f(((const short*)&a1)[ee]) * w1sel_a;
            facc[2][ee] += bf2f(((const short*)&a2)[ee]) * wA.y;
        }
    }

    // every lane holds full denominators (broadcast scalar loads)
    float inv0 = (den0 > 0.f) ? 1.f / den0 : 0.f;
    float inv1 = (den1 > 0.f) ? 1.f / den1 : 0.f;
    short* yrow = Y + (long)u * HS;
    short4 o0, o1, o2;
#pragma unroll
    for (int ee = 0; ee < 4; ++ee) {
        ((short*)&o0)[ee] = f2bf(fmaxf(facc[0][ee] * inv0, 0.f));                         // cols < 256: head0
        ((short*)&o1)[ee] = f2bf(fmaxf(facc[1][ee] * ((mid + ee < UHALF) ? inv0 : inv1), 0.f));
        int c2 = it2 * 4 + ee;
        ((short*)&o2)[ee] = (c2 < CDIM) ? f2bf(fmaxf(facc[2][ee] * inv1, 0.f)) : (short)0;
    }
    ((short4*)yrow)[it0] = o0;
    ((short4*)yrow)[it1] = o1;
    if (has2) ((short4*)yrow)[it2] = o2;
}

// ---------------- decoder (R11 best form) ----------------
__global__ __launch_bounds__(256) void decode_kernel(const short* __restrict__ O, const int* __restrict__ r_idx,
                                                     const int* __restrict__ c_idx, const float* __restrict__ wp,
                                                     const float* __restrict__ dec_b, float* __restrict__ out, int M) {
    int wave = threadIdx.x >> 6, lane = threadIdx.x & 63;
    long m = (long)blockIdx.x * 4 + wave;
    if (m >= M) return;
    int r = r_idx[m], c = c_idx[m];
    const short4* orow = (const short4*)(O + (long)r * HS);
    const short4* crow = (const short4*)(O + (long)c * HS);
    const float4* wv = (const float4*)wp;
    float s = 0.f;
    for (int it = lane; it < HS / 4; it += 64) {
        short4 o = orow[it];
        short4 q = crow[it];
        float4 w = wv[it];
        s += fabsf(bf2f(o.x) - bf2f(q.x)) * w.x;
        s += fabsf(bf2f(o.y) - bf2f(q.y)) * w.y;
        s += fabsf(bf2f(o.z) - bf2f(q.z)) * w.z;
        s += fabsf(bf2f(o.w) - bf2f(q.w)) * w.w;
    }
    for (int d = 32; d; d >>= 1) s += __shfl_down(s, d);
    if (lane == 0) out[m] = s + dec_b[0];
}

extern "C" void kernel_launch(void* const* d_in, const int* in_sizes, int n_in,
                              void* d_out, int out_size, void* d_ws, size_t ws_size,
                              hipStream_t stream) {
    (void)n_in; (void)out_size; (void)ws_size;
    const float* node_feats = (const float*)d_in[0];
    const int* edges = (const int*)d_in[1];
    const int* r_idx = (const int*)d_in[2];
    const int* c_idx = (const int*)d_in[3];
    const float* kmats[3] = {(const float*)d_in[4], (const float*)d_in[6], (const float*)d_in[8]};
    const float* amats[3] = {(const float*)d_in[5], (const float*)d_in[7], (const float*)d_in[9]};
    const float* dec_w = (const float*)d_in[10];
    const float* dec_b = (const float*)d_in[11];
    float* out = (float*)d_out;

    const int F0 = 256;
    const int N = in_sizes[0] / F0;
    const int E = in_sizes[1] / 2;
    const int M = in_sizes[2];
    const int KP1 = 256;
    const int KP2 = HS;   // 704

    char* ws = (char*)d_ws;
    size_t off = 0;
    auto alloc = [&](size_t bytes) -> void* {
        void* p = ws + off;
        off += (bytes + 255) & ~(size_t)255;
        return p;
    };
    // Workspace ~60.5 MB (under the R5-proven budget).
    // layer-0 bf16 input (N x 256) lives in the low bytes of Xb (stride 256);
    // layer-0's GEMM reads it before layer-0's aggregate overwrites Xb (stride 704).
    short* hb   = (short*)alloc((size_t)N * HS * 2);
    short* Xb   = (short*)alloc((size_t)N * HS * 2);
    short* Bt   = (short*)alloc((size_t)NPAD * KP2 * 2);
    float* asrc = (float*)alloc(HS * 4);
    float* adst = (float*)alloc(HS * 4);
    float* decw = (float*)alloc(HS * 4);
    float* s_src = (float*)alloc((size_t)2 * N * 4);
    float* s_dst = (float*)alloc((size_t)2 * N * 4);
    float2* ew   = (float2*)alloc((size_t)E * 8);
    int* offs = (int*)alloc((size_t)(N + 1) * 4);
    int* cnt = (int*)alloc((size_t)N * 4);
    int* fill = (int*)alloc((size_t)N * 4);
    int* csr_dst = (int*)alloc((size_t)E * 4);
    int* csr_srcn = (int*)alloc((size_t)E * 4);

    hipMemsetAsync(cnt, 0, (size_t)N * 4, stream);
    hipMemsetAsync(fill, 0, (size_t)N * 4, stream);

    count_kernel<<<(E + 255) / 256, 256, 0, stream>>>(edges, cnt, E);
    scan_kernel<<<1, 1024, 0, stream>>>(cnt, offs, N);
    fill_kernel<<<(E + 255) / 256, 256, 0, stream>>>(edges, offs, fill, csr_dst, csr_srcn, E);

    long x0t = (long)N * KP1;
    cvt_bf16<<<(int)((x0t + 255) / 256), 256, 0, stream>>>(node_feats, Xb, x0t);

    for (int l = 0; l < 3; ++l) {
        int Kpad = (l == 0) ? KP1 : KP2;
        long bt = (long)NPAD * Kpad;
        pack_layer<<<(int)((bt + 255) / 256), 256, 0, stream>>>(kmats[l], Bt, (l == 0) ? F0 : CDIM, Kpad,
                                                                amats[l], asrc, adst,
                                                                dec_w, decw, (l == 0) ? 1 : 0);
        int nbx = (N + TBM - 1) / TBM;
        gemm_mfma<<<nbx * NBY2, 512, 0, stream>>>(Xb, Bt, hb, N, Kpad);
        score_kernel<<<(N + 3) / 4, 256, 0, stream>>>(hb, asrc, adst, s_src, s_dst, N);
        ew_kernel<<<(E + 255) / 256, 256, 0, stream>>>(csr_srcn, csr_dst, s_src, s_dst, ew, N, E);
        aggregate_kernel<<<(N + 3) / 4, 256, 0, stream>>>(hb, ew, offs, csr_dst, Xb, N);
    }
    decode_kernel<<<(M + 3) / 4, 256, 0, stream>>>(Xb, r_idx, c_idx, decw, dec_b, out, M);
}